// Round 1
// baseline (125.160 us; speedup 1.0000x reference)
//
#include <hip/hip_runtime.h>
#include <stdint.h>

typedef __attribute__((ext_vector_type(8))) short short8;
typedef __attribute__((ext_vector_type(4))) float f32x4;
typedef unsigned short ushort_t;

// fp32 -> bf16 round-to-nearest-even
__device__ __forceinline__ ushort_t f2bf(float f) {
  uint32_t u = __float_as_uint(f);
  u += 0x7fffu + ((u >> 16) & 1u);
  return (ushort_t)(u >> 16);
}

// async global->LDS, 16B per lane; LDS dest is wave-uniform base + lane*16
__device__ __forceinline__ void load_lds16(const ushort_t* g, ushort_t* l) {
  __builtin_amdgcn_global_load_lds(
      (const __attribute__((address_space(1))) uint32_t*)g,
      (__attribute__((address_space(3))) uint32_t*)l, 16, 0, 0);
}

// --- K1: deg + dis + convert (A + I) to bf16. One wave per row. -------------
__global__ __launch_bounds__(256) void k_deg_convA(
    const float* __restrict__ A, ushort_t* __restrict__ Abf,
    float* __restrict__ dis) {
  const int row = blockIdx.x * 4 + (threadIdx.x >> 6);  // b*512 + n
  const int lane = threadIdx.x & 63;
  const int n = row & 511;
  const float2* src = (const float2*)(A + (size_t)row * 512);
  uint32_t* dst = (uint32_t*)(Abf + (size_t)row * 512);
  float s = 0.0f;
#pragma unroll
  for (int i = 0; i < 4; ++i) {
    const int idx = i * 64 + lane;  // float2 index; elements 2*idx, 2*idx+1
    float2 v = src[idx];
    float v0 = v.x + (idx * 2 == n ? 1.0f : 0.0f);      // fold identity
    float v1 = v.y + (idx * 2 + 1 == n ? 1.0f : 0.0f);
    dst[idx] = (uint32_t)f2bf(v0) | ((uint32_t)f2bf(v1) << 16);
    s += v0 + v1;
  }
#pragma unroll
  for (int off = 32; off > 0; off >>= 1) s += __shfl_down(s, off, 64);
  if (lane == 0) dis[row] = rsqrtf(s + 1e-8f);
}

// --- fp32 -> bf16 bulk convert (H, W) ---------------------------------------
__global__ __launch_bounds__(256) void k_conv(const float4* __restrict__ src,
                                              ushort_t* __restrict__ dst,
                                              int n4) {
  int i = blockIdx.x * 256 + threadIdx.x;
  if (i >= n4) return;
  float4 v = src[i];
  uint32_t p0 = (uint32_t)f2bf(v.x) | ((uint32_t)f2bf(v.y) << 16);
  uint32_t p1 = (uint32_t)f2bf(v.z) | ((uint32_t)f2bf(v.w) << 16);
  ((uint2*)dst)[i] = make_uint2(p0, p1);
}

// --- K2: Gt[b][o][m] = (sum_i W[o,i]*H[b,m,i] + bias[o]) * dis[b,m] --------
// C-tile 128(o) x 128(m); A-operand = W (row-major, k=i contiguous);
// B-operand staged as [col=m][k=i] directly from H rows.
__global__ __launch_bounds__(256) void k_gemm_gt(
    const ushort_t* __restrict__ Wbf,  // [256][256]
    const ushort_t* __restrict__ Hbf,  // [32][512][256]
    const float* __restrict__ bias,    // [256]
    const float* __restrict__ dis,     // [32*512]
    ushort_t* __restrict__ Gt) {       // [32][256][512]
  __shared__ ushort_t As[128 * 32];
  __shared__ ushort_t Bs[128 * 32];
  const int batch = blockIdx.z;
  const int ot0 = blockIdx.y * 128;
  const int mt0 = blockIdx.x * 128;
  const int tid = threadIdx.x;
  const int lane = tid & 63, wv = tid >> 6;
  const int wm = wv & 1, wn = wv >> 1;
  const int lr = lane & 15, q = lane >> 4;
  const int rstage = lane >> 2;       // row within 16-row chunk
  const int koff = (lane & 3) * 8;    // element offset in 32-wide K slab

  const ushort_t* Hb = Hbf + (size_t)batch * 512 * 256;

  f32x4 zero = {0.f, 0.f, 0.f, 0.f};
  f32x4 acc[4][4];
#pragma unroll
  for (int i = 0; i < 4; ++i)
#pragma unroll
    for (int j = 0; j < 4; ++j) acc[i][j] = zero;

  for (int k0 = 0; k0 < 256; k0 += 32) {
#pragma unroll
    for (int j = 0; j < 2; ++j) {
      const int c = wv * 2 + j;
      const int rl = c * 16 + rstage;
      load_lds16(Wbf + (size_t)(ot0 + rl) * 256 + k0 + koff, &As[c * 512]);
      load_lds16(Hb + (size_t)(mt0 + rl) * 256 + k0 + koff, &Bs[c * 512]);
    }
    __syncthreads();
    short8 af[4], bfr[4];
#pragma unroll
    for (int mt = 0; mt < 4; ++mt)
      af[mt] = *(const short8*)&As[(wm * 64 + mt * 16 + lr) * 32 + q * 8];
#pragma unroll
    for (int nt = 0; nt < 4; ++nt)
      bfr[nt] = *(const short8*)&Bs[(wn * 64 + nt * 16 + lr) * 32 + q * 8];
#pragma unroll
    for (int mt = 0; mt < 4; ++mt)
#pragma unroll
      for (int nt = 0; nt < 4; ++nt)
        acc[mt][nt] = __builtin_amdgcn_mfma_f32_16x16x32_bf16(
            af[mt], bfr[nt], acc[mt][nt], 0, 0, 0);
    __syncthreads();
  }

  float dm[4];
#pragma unroll
  for (int nt = 0; nt < 4; ++nt)
    dm[nt] = dis[batch * 512 + mt0 + wn * 64 + nt * 16 + lr];
#pragma unroll
  for (int mt = 0; mt < 4; ++mt) {
    const int ob = ot0 + wm * 64 + mt * 16 + q * 4;
    float bs[4];
#pragma unroll
    for (int r = 0; r < 4; ++r) bs[r] = bias[ob + r];
#pragma unroll
    for (int nt = 0; nt < 4; ++nt) {
      const int m = mt0 + wn * 64 + nt * 16 + lr;
      ushort_t* dstp = Gt + ((size_t)batch * 256 + ob) * 512 + m;
#pragma unroll
      for (int r = 0; r < 4; ++r)
        dstp[(size_t)r * 512] = f2bf((acc[mt][nt][r] + bs[r]) * dm[nt]);
    }
  }
}

// --- K3: out[b][n][o] = relu( (Ahat @ G)[n,o] * dis[b,n] * mask[b,n] ) ------
// C-tile 128(n) x 128(o); A-operand = Ahat_bf16 rows; B-operand staged
// [col=o][k=m] directly from Gt rows.
__global__ __launch_bounds__(256) void k_gemm_out(
    const ushort_t* __restrict__ Abf,  // [32][512][512] (A + I)
    const ushort_t* __restrict__ Gt,   // [32][256][512]
    const float* __restrict__ dis,     // [32*512]
    const float* __restrict__ mask,    // [32*512]
    float* __restrict__ out) {         // [32][512][256]
  __shared__ ushort_t As[128 * 32];
  __shared__ ushort_t Bs[128 * 32];
  const int batch = blockIdx.z;
  const int nt0 = blockIdx.x * 128;
  const int ot0 = blockIdx.y * 128;
  const int tid = threadIdx.x;
  const int lane = tid & 63, wv = tid >> 6;
  const int wm = wv & 1, wn = wv >> 1;
  const int lr = lane & 15, q = lane >> 4;
  const int rstage = lane >> 2;
  const int koff = (lane & 3) * 8;

  const ushort_t* Ab = Abf + (size_t)batch * 512 * 512;
  const ushort_t* Gb = Gt + (size_t)batch * 256 * 512;

  f32x4 zero = {0.f, 0.f, 0.f, 0.f};
  f32x4 acc[4][4];
#pragma unroll
  for (int i = 0; i < 4; ++i)
#pragma unroll
    for (int j = 0; j < 4; ++j) acc[i][j] = zero;

  for (int k0 = 0; k0 < 512; k0 += 32) {
#pragma unroll
    for (int j = 0; j < 2; ++j) {
      const int c = wv * 2 + j;
      const int rl = c * 16 + rstage;
      load_lds16(Ab + (size_t)(nt0 + rl) * 512 + k0 + koff, &As[c * 512]);
      load_lds16(Gb + (size_t)(ot0 + rl) * 512 + k0 + koff, &Bs[c * 512]);
    }
    __syncthreads();
    short8 af[4], bfr[4];
#pragma unroll
    for (int mt = 0; mt < 4; ++mt)
      af[mt] = *(const short8*)&As[(wm * 64 + mt * 16 + lr) * 32 + q * 8];
#pragma unroll
    for (int nt = 0; nt < 4; ++nt)
      bfr[nt] = *(const short8*)&Bs[(wn * 64 + nt * 16 + lr) * 32 + q * 8];
#pragma unroll
    for (int mt = 0; mt < 4; ++mt)
#pragma unroll
      for (int nt = 0; nt < 4; ++nt)
        acc[mt][nt] = __builtin_amdgcn_mfma_f32_16x16x32_bf16(
            af[mt], bfr[nt], acc[mt][nt], 0, 0, 0);
    __syncthreads();
  }

#pragma unroll
  for (int mt = 0; mt < 4; ++mt) {
    const int nb = nt0 + wm * 64 + mt * 16 + q * 4;
    float sc[4];
#pragma unroll
    for (int r = 0; r < 4; ++r) {
      const int gn = batch * 512 + nb + r;
      sc[r] = dis[gn] * mask[gn];
    }
#pragma unroll
    for (int nt = 0; nt < 4; ++nt) {
      const int o = ot0 + wn * 64 + nt * 16 + lr;
      float* dstp = out + ((size_t)(batch * 512 + nb)) * 256 + o;
#pragma unroll
      for (int r = 0; r < 4; ++r) {
        float v = acc[mt][nt][r] * sc[r];
        dstp[(size_t)r * 256] = v > 0.0f ? v : 0.0f;
      }
    }
  }
}

extern "C" void kernel_launch(void* const* d_in, const int* in_sizes, int n_in,
                              void* d_out, int out_size, void* d_ws,
                              size_t ws_size, hipStream_t stream) {
  const float* H = (const float*)d_in[0];     // [32][512][256]
  const float* A = (const float*)d_in[1];     // [32][512][512]
  const float* mask = (const float*)d_in[2];  // [32][512]
  const float* W = (const float*)d_in[3];     // [256][256]
  const float* b = (const float*)d_in[4];     // [256]
  float* out = (float*)d_out;                 // [32][512][256]

  char* ws = (char*)d_ws;
  ushort_t* Abf = (ushort_t*)ws;                          // 16,777,216 B
  ushort_t* Hbf = (ushort_t*)(ws + 16777216);             //  8,388,608 B
  ushort_t* Wbf = (ushort_t*)(ws + 16777216 + 8388608);   //    131,072 B
  ushort_t* Gt = (ushort_t*)(ws + 16777216 + 8388608 + 131072);  // 8,388,608 B
  float* dis = (float*)(ws + 16777216 + 8388608 + 131072 + 8388608);  // 65,536 B

  // 1) deg -> dis, and (A+I) -> bf16
  k_deg_convA<<<4096, 256, 0, stream>>>(A, Abf, dis);
  // 2) H, W -> bf16
  k_conv<<<1048576 / 256, 256, 0, stream>>>((const float4*)H, Hbf, 1048576);
  k_conv<<<16384 / 256, 256, 0, stream>>>((const float4*)W, Wbf, 16384);
  // 3) Gt = dis * (W @ H^T + b)   [bf16, transposed layout]
  k_gemm_gt<<<dim3(4, 2, 32), 256, 0, stream>>>(Wbf, Hbf, b, dis, Gt);
  // 4) out = relu(mask * dis * (Ahat @ G))
  k_gemm_out<<<dim3(4, 2, 32), 256, 0, stream>>>(Abf, Gt, dis, mask, out);
}

// Round 2
// 117.602 us; speedup vs baseline: 1.0643x; 1.0643x over previous
//
#include <hip/hip_runtime.h>
#include <stdint.h>

typedef __attribute__((ext_vector_type(8))) short short8;
typedef __attribute__((ext_vector_type(4))) float f32x4;
typedef unsigned short ushort_t;

// fp32 -> bf16 round-to-nearest-even
__device__ __forceinline__ ushort_t f2bf(float f) {
  uint32_t u = __float_as_uint(f);
  u += 0x7fffu + ((u >> 16) & 1u);
  return (ushort_t)(u >> 16);
}

__device__ __forceinline__ uint2 pack4(float4 v) {
  return make_uint2((uint32_t)f2bf(v.x) | ((uint32_t)f2bf(v.y) << 16),
                    (uint32_t)f2bf(v.z) | ((uint32_t)f2bf(v.w) << 16));
}

// async global->LDS, 16B per lane; LDS dest = wave-uniform base + lane*16
__device__ __forceinline__ void load_lds16(const ushort_t* g, ushort_t* l) {
  __builtin_amdgcn_global_load_lds(
      (const __attribute__((address_space(1))) uint32_t*)g,
      (__attribute__((address_space(3))) uint32_t*)l, 16, 0, 0);
}

// --- K1: fused prep ---------------------------------------------------------
// job A: per-row deg -> dis, write (A+I) as bf16    (one wave per row)
// job B: H fp32 -> bf16 (one float4 per thread)
// job C: W fp32 -> bf16 (blocks 0..63)
__global__ __launch_bounds__(256) void k_prep(
    const float4* __restrict__ A4, const float4* __restrict__ H4,
    const float4* __restrict__ W4, ushort_t* __restrict__ Abf,
    ushort_t* __restrict__ Hbf, ushort_t* __restrict__ Wbf,
    float* __restrict__ dis) {
  const int tid = threadIdx.x;
  // H convert: 4096*256 threads cover 1,048,576 float4s
  {
    const int i = blockIdx.x * 256 + tid;
    ((uint2*)Hbf)[i] = pack4(H4[i]);
  }
  // W convert: 64*256 = 16384 float4s
  if (blockIdx.x < 64) {
    const int i = blockIdx.x * 256 + tid;
    ((uint2*)Wbf)[i] = pack4(W4[i]);
  }
  // A row job
  const int row = blockIdx.x * 4 + (tid >> 6);  // b*512 + n
  const int lane = tid & 63;
  const int n = row & 511;
  const float4* src = A4 + (size_t)row * 128;
  uint2* dst = (uint2*)(Abf + (size_t)row * 512);
  float s = 0.0f;
#pragma unroll
  for (int i = 0; i < 2; ++i) {
    const int idx = i * 64 + lane;
    float4 v = src[idx];
    const int c0 = idx * 4;
    v.x += (float)(c0 == n);  // fold identity into the bf16 copy
    v.y += (float)(c0 + 1 == n);
    v.z += (float)(c0 + 2 == n);
    v.w += (float)(c0 + 3 == n);
    s += (v.x + v.y) + (v.z + v.w);
    dst[idx] = pack4(v);
  }
#pragma unroll
  for (int off = 32; off > 0; off >>= 1) s += __shfl_down(s, off, 64);
  if (lane == 0) dis[row] = rsqrtf(s + 1e-8f);
}

// --- K2: Gt[b][o][m] = (sum_i W[o,i]*H[b,m,i] + bias[o]) * dis[b,m] ---------
// tile 64(o) x 128(m), K=256; double-buffered single-barrier K-loop.
// grid 512, bid = yo*128 + batch*4 + xm  (H-sharers land on one XCD)
__global__ __launch_bounds__(256) void k_gemm_gt(
    const ushort_t* __restrict__ Wbf,  // [256][256]
    const ushort_t* __restrict__ Hbf,  // [32][512][256]
    const float* __restrict__ bias,    // [256]
    const float* __restrict__ dis,     // [32*512]
    ushort_t* __restrict__ Gt) {       // [32][256][512]
  __shared__ ushort_t As[2][64 * 32];   // W rows  (o x k)
  __shared__ ushort_t Bs[2][128 * 32];  // H rows  (m x k)
  const int bid = blockIdx.x;
  const int yo = bid >> 7;      // o-tile 0..3
  const int rr = bid & 127;
  const int batch = rr >> 2;    // 0..31
  const int xm = rr & 3;        // m-tile 0..3
  const int ot0 = yo * 64, mt0 = xm * 128;
  const int tid = threadIdx.x, lane = tid & 63, wv = tid >> 6;
  const int wo = wv & 1;    // o half (2 x 32)
  const int wmh = wv >> 1;  // m half (2 x 64)
  const int lr = lane & 15, q = lane >> 4;
  const int rstage = lane >> 2, koff = (lane & 3) * 8;
  const ushort_t* Hb = Hbf + (size_t)batch * 512 * 256;

  f32x4 acc[2][4];
#pragma unroll
  for (int i = 0; i < 2; ++i)
#pragma unroll
    for (int j = 0; j < 4; ++j) acc[i][j] = {0.f, 0.f, 0.f, 0.f};

  auto stage = [&](int k0, int p) {
    load_lds16(Wbf + (size_t)(ot0 + wv * 16 + rstage) * 256 + k0 + koff,
               &As[p][wv * 512]);
#pragma unroll
    for (int j = 0; j < 2; ++j) {
      const int c = wv * 2 + j;
      load_lds16(Hb + (size_t)(mt0 + c * 16 + rstage) * 256 + k0 + koff,
                 &Bs[p][c * 512]);
    }
  };
  auto compute = [&](int p) {
    short8 af[2], bfr[4];
#pragma unroll
    for (int mt = 0; mt < 2; ++mt)
      af[mt] = *(const short8*)&As[p][(wo * 32 + mt * 16 + lr) * 32 + q * 8];
#pragma unroll
    for (int nt = 0; nt < 4; ++nt)
      bfr[nt] = *(const short8*)&Bs[p][(wmh * 64 + nt * 16 + lr) * 32 + q * 8];
#pragma unroll
    for (int mt = 0; mt < 2; ++mt)
#pragma unroll
      for (int nt = 0; nt < 4; ++nt)
        acc[mt][nt] = __builtin_amdgcn_mfma_f32_16x16x32_bf16(
            af[mt], bfr[nt], acc[mt][nt], 0, 0, 0);
  };

  stage(0, 0);
#pragma unroll
  for (int it = 0; it < 8; ++it) {
    __syncthreads();  // tile it landed; everyone done with buf (it+1)&1
    if (it + 1 < 8) stage((it + 1) * 32, (it + 1) & 1);  // overlaps compute
    compute(it & 1);
  }

  float dm[4];
#pragma unroll
  for (int nt = 0; nt < 4; ++nt)
    dm[nt] = dis[batch * 512 + mt0 + wmh * 64 + nt * 16 + lr];
#pragma unroll
  for (int mt = 0; mt < 2; ++mt) {
    const int ob = ot0 + wo * 32 + mt * 16 + q * 4;
    float bs[4];
#pragma unroll
    for (int r = 0; r < 4; ++r) bs[r] = bias[ob + r];
#pragma unroll
    for (int nt = 0; nt < 4; ++nt) {
      const int m = mt0 + wmh * 64 + nt * 16 + lr;
      ushort_t* dstp = Gt + ((size_t)batch * 256 + ob) * 512 + m;
#pragma unroll
      for (int r = 0; r < 4; ++r)
        dstp[(size_t)r * 512] = f2bf((acc[mt][nt][r] + bs[r]) * dm[nt]);
    }
  }
}

// --- K3: out[b][n][o] = relu( (Ahat @ G)[n,o] * dis[b,n] * mask[b,n] ) ------
// tile 128(n) x 64(o), K=512; double-buffered single-barrier K-loop.
// grid 512, bid = yo*128 + batch*4 + xn  (Ahat-sharers land on one XCD)
__global__ __launch_bounds__(256) void k_gemm_out(
    const ushort_t* __restrict__ Abf,  // [32][512][512] (A + I)
    const ushort_t* __restrict__ Gt,   // [32][256][512]
    const float* __restrict__ dis,     // [32*512]
    const float* __restrict__ mask,    // [32*512]
    float* __restrict__ out) {         // [32][512][256]
  __shared__ ushort_t As[2][128 * 32];  // Ahat rows (n x k)
  __shared__ ushort_t Bs[2][64 * 32];   // Gt rows   (o x k)
  const int bid = blockIdx.x;
  const int yo = bid >> 7;      // o-tile 0..3
  const int rr = bid & 127;
  const int batch = rr >> 2;    // 0..31
  const int xn = rr & 3;        // n-tile 0..3
  const int nt0 = xn * 128, ot0 = yo * 64;
  const int tid = threadIdx.x, lane = tid & 63, wv = tid >> 6;
  const int wnh = wv & 1;   // n half (2 x 64)
  const int woh = wv >> 1;  // o half (2 x 32)
  const int lr = lane & 15, q = lane >> 4;
  const int rstage = lane >> 2, koff = (lane & 3) * 8;
  const ushort_t* Ab = Abf + (size_t)batch * 512 * 512;
  const ushort_t* Gb = Gt + (size_t)batch * 256 * 512;

  f32x4 acc[4][2];
#pragma unroll
  for (int i = 0; i < 4; ++i)
#pragma unroll
    for (int j = 0; j < 2; ++j) acc[i][j] = {0.f, 0.f, 0.f, 0.f};

  auto stage = [&](int k0, int p) {
#pragma unroll
    for (int j = 0; j < 2; ++j) {
      const int c = wv * 2 + j;
      load_lds16(Ab + (size_t)(nt0 + c * 16 + rstage) * 512 + k0 + koff,
                 &As[p][c * 512]);
    }
    load_lds16(Gb + (size_t)(ot0 + wv * 16 + rstage) * 512 + k0 + koff,
               &Bs[p][wv * 512]);
  };
  auto compute = [&](int p) {
    short8 af[4], bfr[2];
#pragma unroll
    for (int mt = 0; mt < 4; ++mt)
      af[mt] = *(const short8*)&As[p][(wnh * 64 + mt * 16 + lr) * 32 + q * 8];
#pragma unroll
    for (int nt = 0; nt < 2; ++nt)
      bfr[nt] = *(const short8*)&Bs[p][(woh * 32 + nt * 16 + lr) * 32 + q * 8];
#pragma unroll
    for (int mt = 0; mt < 4; ++mt)
#pragma unroll
      for (int nt = 0; nt < 2; ++nt)
        acc[mt][nt] = __builtin_amdgcn_mfma_f32_16x16x32_bf16(
            af[mt], bfr[nt], acc[mt][nt], 0, 0, 0);
  };

  stage(0, 0);
#pragma unroll
  for (int it = 0; it < 16; ++it) {
    __syncthreads();
    if (it + 1 < 16) stage((it + 1) * 32, (it + 1) & 1);
    compute(it & 1);
  }

#pragma unroll
  for (int mt = 0; mt < 4; ++mt) {
    const int nb = nt0 + wnh * 64 + mt * 16 + q * 4;
    float sc[4];
#pragma unroll
    for (int r = 0; r < 4; ++r) {
      const int gn = batch * 512 + nb + r;
      sc[r] = dis[gn] * mask[gn];
    }
#pragma unroll
    for (int nt = 0; nt < 2; ++nt) {
      const int o = ot0 + woh * 32 + nt * 16 + lr;
      float* dstp = out + ((size_t)(batch * 512 + nb)) * 256 + o;
#pragma unroll
      for (int r = 0; r < 4; ++r) {
        float v = acc[mt][nt][r] * sc[r];
        dstp[(size_t)r * 256] = v > 0.0f ? v : 0.0f;
      }
    }
  }
}

extern "C" void kernel_launch(void* const* d_in, const int* in_sizes, int n_in,
                              void* d_out, int out_size, void* d_ws,
                              size_t ws_size, hipStream_t stream) {
  const float* H = (const float*)d_in[0];     // [32][512][256]
  const float* A = (const float*)d_in[1];     // [32][512][512]
  const float* mask = (const float*)d_in[2];  // [32][512]
  const float* W = (const float*)d_in[3];     // [256][256]
  const float* b = (const float*)d_in[4];     // [256]
  float* out = (float*)d_out;                 // [32][512][256]

  char* ws = (char*)d_ws;
  ushort_t* Abf = (ushort_t*)ws;                                 // 16 MiB
  ushort_t* Hbf = (ushort_t*)(ws + 16777216);                    // 8 MiB
  ushort_t* Wbf = (ushort_t*)(ws + 16777216 + 8388608);          // 128 KiB
  ushort_t* Gt = (ushort_t*)(ws + 16777216 + 8388608 + 131072);  // 8 MiB
  float* dis = (float*)(ws + 16777216 + 8388608 + 131072 + 8388608);

  // 1) fused: deg->dis, (A+I)->bf16, H->bf16, W->bf16
  k_prep<<<4096, 256, 0, stream>>>((const float4*)A, (const float4*)H,
                                   (const float4*)W, Abf, Hbf, Wbf, dis);
  // 2) Gt = dis * (W @ H^T + b)   [bf16, transposed layout]
  k_gemm_gt<<<512, 256, 0, stream>>>(Wbf, Hbf, b, dis, Gt);
  // 3) out = relu(mask * dis * (Ahat @ G))
  k_gemm_out<<<512, 256, 0, stream>>>(Abf, Gt, dis, mask, out);
}